// Round 2
// baseline (1836.190 us; speedup 1.0000x reference)
//
#include <hip/hip_runtime.h>

// B=256, T=2048, D_IN=64, D_H=64, D_OUT=1
#define TSEQ  2048
#define DH    64
#define CHUNK 8     // steps per LDS chunk

typedef float f32x2  __attribute__((ext_vector_type(2)));
typedef float f32x16 __attribute__((ext_vector_type(16)));
typedef short bf16x8 __attribute__((ext_vector_type(8)));

union CU { float4 f4[4]; f32x16 v; };
union B8 { unsigned u[4]; bf16x8 v; };

__device__ inline unsigned cvt_pk_bf16(float lo, float hi) {
    unsigned d;
    asm("v_cvt_pk_bf16_f32 %0, %1, %2" : "=v"(d) : "v"(lo), "v"(hi));
    return d;
}
// a' = [a_lo, b_lo], b' = [a_hi, b_hi]
__device__ inline void plane_swap(unsigned &a, unsigned &b) {
    asm("v_permlane32_swap_b32 %0, %1" : "+v"(a), "+v"(b));
}
__device__ inline f32x2 pk_fma(f32x2 a, f32x2 b, f32x2 c) {
    f32x2 d; asm("v_pk_fma_f32 %0, %1, %2, %3" : "=v"(d) : "v"(a), "v"(b), "v"(c)); return d;
}
__device__ inline f32x2 pk_mul(f32x2 a, f32x2 b) {
    f32x2 d; asm("v_pk_mul_f32 %0, %1, %2" : "=v"(d) : "v"(a), "v"(b)); return d;
}
__device__ inline f32x16 mfma_bf16(bf16x8 a, bf16x8 b, f32x16 c) {
    return __builtin_amdgcn_mfma_f32_32x32x16_bf16(a, b, c, 0, 0, 0);
}
__device__ inline f32x16 zero16() {
    f32x16 v;
    #pragma unroll
    for (int i = 0; i < 16; ++i) v[i] = 0.f;
    return v;
}
__device__ inline f32x2 splat2(float k) { f32x2 v; v.x = k; v.y = k; return v; }

// A-fragment for v_mfma_f32_32x32x16_bf16: lane supplies row `row`,
// k = k0..k0+7 (8 consecutive f32 -> 4 packed bf16 regs).
__device__ inline bf16x8 w_frag(const float* __restrict__ W, int row, int k0) {
    const float4* p = (const float4*)(W + row * DH + k0);
    float4 f0 = p[0], f1 = p[1];
    B8 r;
    r.u[0] = cvt_pk_bf16(f0.x, f0.y);
    r.u[1] = cvt_pk_bf16(f0.z, f0.w);
    r.u[2] = cvt_pk_bf16(f1.x, f1.y);
    r.u[3] = cvt_pk_bf16(f1.z, f1.w);
    return r.v;
}

// One block per group of 32 batches. wave0 = serial recurrence (MFMA),
// wave1 = producer of a[t] = W_xh @ x_t in C/D layout into LDS dbuf.
__global__ __launch_bounds__(128, 1)
void rnn_mfma(const float* __restrict__ x, const int* __restrict__ slen,
              const float* __restrict__ W_xh, const float* __restrict__ W_hh,
              const float* __restrict__ W_out, const float* __restrict__ b_out,
              float* __restrict__ out)
{
    // [buf][step][lane][8 float4], XOR-swizzled in last index to avoid
    // 128B-stride bank aliasing on ds_read_b128. 128 KiB total.
    __shared__ float4 abuf[2][CHUNK][64][8];

    const int g   = blockIdx.x;
    const int wv  = threadIdx.x >> 6;
    const int l   = threadIdx.x & 63;
    const int col = l & 31;          // batch column within group
    const int hi  = l >> 5;
    const int b   = 32 * g + col;
    const int swz = l & 7;

    const int Ll = slen[b];
    int mx = Ll;
    #pragma unroll
    for (int off = 32; off > 0; off >>= 1) mx = max(mx, __shfl_xor(mx, off, 64));
    const int NC = (mx + CHUNK) / CHUNK;     // ceil((maxL+1)/CHUNK), <= 256

    if (wv == 1) {
        // ---------------- producer ----------------
        bf16x8 A0[4], A1[4];
        #pragma unroll
        for (int kt = 0; kt < 4; ++kt) {
            A0[kt] = w_frag(W_xh, col,      16 * kt + 8 * hi);
            A1[kt] = w_frag(W_xh, 32 + col, 16 * kt + 8 * hi);
        }
        const float* xb = x + (size_t)b * TSEQ * DH;

        auto produce = [&](int pc) {
            #pragma unroll
            for (int s = 0; s < CHUNK; ++s) {
                const int t = pc * CHUNK + s;
                if (t < TSEQ) {
                    const float4* xf = (const float4*)(xb + (size_t)t * DH);
                    bf16x8 Bf[4];
                    #pragma unroll
                    for (int kt = 0; kt < 4; ++kt) {
                        float4 f0 = xf[4 * kt + 2 * hi];
                        float4 f1 = xf[4 * kt + 2 * hi + 1];
                        B8 r;
                        r.u[0] = cvt_pk_bf16(f0.x, f0.y);
                        r.u[1] = cvt_pk_bf16(f0.z, f0.w);
                        r.u[2] = cvt_pk_bf16(f1.x, f1.y);
                        r.u[3] = cvt_pk_bf16(f1.z, f1.w);
                        Bf[kt] = r.v;
                    }
                    CU c0, c1;
                    c0.v = zero16(); c1.v = zero16();
                    #pragma unroll
                    for (int kt = 0; kt < 4; ++kt) {
                        c0.v = mfma_bf16(A0[kt], Bf[kt], c0.v);
                        c1.v = mfma_bf16(A1[kt], Bf[kt], c1.v);
                    }
                    float4* dst = &abuf[pc & 1][s][l][0];
                    #pragma unroll
                    for (int r8 = 0; r8 < 4; ++r8) dst[r8 ^ swz]       = c0.f4[r8];
                    #pragma unroll
                    for (int r8 = 0; r8 < 4; ++r8) dst[(4 + r8) ^ swz] = c1.f4[r8];
                }
            }
        };

        produce(0);
        __syncthreads();
        for (int c = 0; c < NC; ++c) {
            if (c + 1 < NC) produce(c + 1);
            __syncthreads();
        }
    } else {
        // ---------------- consumer (serial recurrence) ----------------
        bf16x8 A0[4], A1[4];
        #pragma unroll
        for (int kt = 0; kt < 4; ++kt) {
            A0[kt] = w_frag(W_hh, col,      16 * kt + 8 * hi);
            A1[kt] = w_frag(W_hh, 32 + col, 16 * kt + 8 * hi);
        }
        f32x2 hcur[16], hsav[16];
        #pragma unroll
        for (int i = 0; i < 16; ++i) { hcur[i] = splat2(0.f); hsav[i] = splat2(0.f); }
        B8 Bf[4];
        #pragma unroll
        for (int kt = 0; kt < 4; ++kt) {
            Bf[kt].u[0] = 0; Bf[kt].u[1] = 0; Bf[kt].u[2] = 0; Bf[kt].u[3] = 0;
        }
        // tanh(z) ~ z*(1 + c3 z^2 + c5 z^4 + c7 z^6 + c9 z^8), |z| <~ 0.9
        const f32x2 C9  = splat2( 0.02186948854f);
        const f32x2 C7  = splat2(-0.05396825397f);
        const f32x2 C5  = splat2( 0.13333333333f);
        const f32x2 C3  = splat2(-0.33333333333f);
        const f32x2 ONE = splat2( 1.0f);

        __syncthreads();   // chunk 0 ready
        CU cc[2][2];
        for (int c = 0; c < NC; ++c) {
            {   // load step 0 of this chunk
                const float4* src = &abuf[c & 1][0][l][0];
                #pragma unroll
                for (int r8 = 0; r8 < 4; ++r8) cc[0][0].f4[r8] = src[r8 ^ swz];
                #pragma unroll
                for (int r8 = 0; r8 < 4; ++r8) cc[0][1].f4[r8] = src[(4 + r8) ^ swz];
            }
            #pragma unroll
            for (int s = 0; s < CHUNK; ++s) {
                if (s + 1 < CHUNK) {   // prefetch next step's a-tile
                    const float4* src = &abuf[c & 1][s + 1][l][0];
                    #pragma unroll
                    for (int r8 = 0; r8 < 4; ++r8) cc[(s + 1) & 1][0].f4[r8] = src[r8 ^ swz];
                    #pragma unroll
                    for (int r8 = 0; r8 < 4; ++r8) cc[(s + 1) & 1][1].f4[r8] = src[(4 + r8) ^ swz];
                }
                const int t = c * CHUNK + s;
                // freeze: h_final = h_t when t == L  (h_t currently in hcur)
                const bool frz = (t == Ll);
                if (__any(frz)) {
                    #pragma unroll
                    for (int i = 0; i < 16; ++i) hsav[i] = frz ? hcur[i] : hsav[i];
                }
                // z = a_t + W_hh @ h   (C-init = a-tile)
                f32x16 z0 = cc[s & 1][0].v, z1 = cc[s & 1][1].v;
                #pragma unroll
                for (int kt = 0; kt < 4; ++kt) {
                    z0 = mfma_bf16(A0[kt], Bf[kt].v, z0);
                    z1 = mfma_bf16(A1[kt], Bf[kt].v, z1);
                }
                // tanh on packed pairs; also produce bf16-packed rows
                unsigned u[16];
                #pragma unroll
                for (int m = 0; m < 8; ++m) {
                    f32x2 zz; zz.x = z0[2 * m]; zz.y = z0[2 * m + 1];
                    f32x2 t2 = pk_mul(zz, zz);
                    f32x2 p  = pk_fma(C9, t2, C7);
                    p = pk_fma(p, t2, C5);
                    p = pk_fma(p, t2, C3);
                    p = pk_fma(p, t2, ONE);
                    f32x2 h = pk_mul(p, zz);
                    hcur[m] = h;
                    u[m] = cvt_pk_bf16(h.x, h.y);
                }
                #pragma unroll
                for (int m = 0; m < 8; ++m) {
                    f32x2 zz; zz.x = z1[2 * m]; zz.y = z1[2 * m + 1];
                    f32x2 t2 = pk_mul(zz, zz);
                    f32x2 p  = pk_fma(C9, t2, C7);
                    p = pk_fma(p, t2, C5);
                    p = pk_fma(p, t2, C3);
                    p = pk_fma(p, t2, ONE);
                    f32x2 h = pk_mul(p, zz);
                    hcur[8 + m] = h;
                    u[8 + m] = cvt_pk_bf16(h.x, h.y);
                }
                // repack C/D-layout h into next-step B-fragments:
                // per k-tile: 2 permlane32_swap assemble rows 16kt+8hi+[0..8)
                #pragma unroll
                for (int kt = 0; kt < 4; ++kt) {
                    unsigned p0  = u[4 * kt + 0];
                    unsigned p0b = u[4 * kt + 1];
                    unsigned p1  = u[4 * kt + 2];
                    unsigned p1b = u[4 * kt + 3];
                    plane_swap(p0, p1);
                    plane_swap(p0b, p1b);
                    Bf[kt].u[0] = p0; Bf[kt].u[1] = p0b;
                    Bf[kt].u[2] = p1; Bf[kt].u[3] = p1b;
                }
            }
            __syncthreads();
        }
        // epilogue: out[b] = sum_j h[j,b] * W_out[j] + b_out
        float acc = 0.f;
        #pragma unroll
        for (int i = 0; i < 16; ++i) {
            const int jt = i >> 3, p = (i >> 1) & 3, qp = i & 1;
            const int r0 = 32 * jt + 8 * p + 4 * hi + 2 * qp;
            acc += hsav[i].x * W_out[r0] + hsav[i].y * W_out[r0 + 1];
        }
        acc += __shfl_xor(acc, 32, 64);
        if (l < 32) out[b] = acc + b_out[0];
    }
}

extern "C" void kernel_launch(void* const* d_in, const int* in_sizes, int n_in,
                              void* d_out, int out_size, void* d_ws, size_t ws_size,
                              hipStream_t stream) {
    const float* x     = (const float*)d_in[0];
    const int*   slen  = (const int*)  d_in[1];
    const float* W_xh  = (const float*)d_in[2];
    const float* W_hh  = (const float*)d_in[3];
    const float* W_out = (const float*)d_in[4];
    const float* b_out = (const float*)d_in[5];
    float* out = (float*)d_out;

    const int B = in_sizes[1];          // 256
    rnn_mfma<<<dim3(B / 32), dim3(128), 0, stream>>>(
        x, slen, W_xh, W_hh, W_out, b_out, out);
}

// Round 3
// 404.645 us; speedup vs baseline: 4.5378x; 4.5378x over previous
//
#include <hip/hip_runtime.h>

// B=256, T=2048, D_IN=64, D_H=64, D_OUT=1
#define TSEQ  2048
#define DH    64
#define CHUNK 64
#define NPROD 3   // producer waves

typedef float f32x2 __attribute__((ext_vector_type(2)));

__device__ inline f32x2 pk_fma(f32x2 a, f32x2 b, f32x2 c) {
    f32x2 d; asm("v_pk_fma_f32 %0, %1, %2, %3" : "=v"(d) : "v"(a), "v"(b), "v"(c)); return d;
}
__device__ inline f32x2 pk_add(f32x2 a, f32x2 b) {
    f32x2 d; asm("v_pk_add_f32 %0, %1, %2" : "=v"(d) : "v"(a), "v"(b)); return d;
}

// One block per batch. Wave 0: serial recurrence. Waves 1..NPROD: produce
// a[t,:] = W_xh @ x_t into LDS double buffer (chunks of 64 steps).
__global__ __launch_bounds__(64 * (NPROD + 1), 1)
void rnn_pk(const float* __restrict__ x, const int* __restrict__ slen,
            const float* __restrict__ W_xh, const float* __restrict__ W_hh,
            const float* __restrict__ W_out, const float* __restrict__ b_out,
            float* __restrict__ out)
{
    __shared__ float a_buf[2][CHUNK][DH];           // 32 KiB
    __shared__ __align__(16) float hbuf[DH];        // h broadcast buffer

    const int b   = blockIdx.x;
    const int wv  = threadIdx.x >> 6;
    const int l   = threadIdx.x & 63;
    const int L   = slen[b];
    const int nch = (L + CHUNK - 1) / CHUNK;

    const float* __restrict__ xb = x + (size_t)b * TSEQ * DH;

    if (wv == 0) {
        // ---------------- consumer: the serial chain ----------------
        // Lane l owns output row l of W_hh, packed as 32 f32x2 pairs.
        f32x2 w[32];
        {
            const f32x2* wr = (const f32x2*)(W_hh + l * DH);
            #pragma unroll
            for (int k = 0; k < 32; ++k) w[k] = wr[k];
        }
        hbuf[l] = 0.0f;       // h_0 = 0
        float h = 0.0f;
        __syncthreads();      // matches producers' post-produce(0) barrier

        const float4* hb4 = (const float4*)hbuf;

        auto step = [&](const float* __restrict__ ap) {
            const float aval = *ap;                       // ds_read_b32 (a_t[l])
            f32x2 a0{0.f,0.f}, a1{0.f,0.f}, a2{0.f,0.f}, a3{0.f,0.f};
            #pragma unroll
            for (int r = 0; r < 16; r += 2) {
                // wave-uniform addresses -> LDS broadcast, conflict-free
                const float4 qa = hb4[r];
                const float4 qb = hb4[r + 1];
                f32x2 p0; p0.x = qa.x; p0.y = qa.y;
                f32x2 p1; p1.x = qa.z; p1.y = qa.w;
                f32x2 p2; p2.x = qb.x; p2.y = qb.y;
                f32x2 p3; p3.x = qb.z; p3.y = qb.w;
                a0 = pk_fma(w[2 * r + 0], p0, a0);
                a1 = pk_fma(w[2 * r + 1], p1, a1);
                a2 = pk_fma(w[2 * r + 2], p2, a2);
                a3 = pk_fma(w[2 * r + 3], p3, a3);
            }
            const f32x2 s = pk_add(pk_add(a0, a1), pk_add(a2, a3));
            float z = s.x + s.y + aval;
            // tanh(z) = 1 - 2/(exp(2z)+1)   (proven exact enough in round 1)
            z = fminf(fmaxf(z, -15.0f), 15.0f);
            const float e2 = __expf(2.0f * z);
            const float hn = fmaf(-2.0f, __builtin_amdgcn_rcpf(e2 + 1.0f), 1.0f);
            hbuf[l] = hn;     // ds_write_b32; same-wave DS ops are in-order,
                              // so next step's broadcast reads see it.
            return hn;
        };

        for (int c = 0; c < nch; ++c) {
            const int base = c << 6;
            const int cnt  = min(CHUNK, L - base);
            const float* __restrict__ ab = &a_buf[c & 1][0][l];
            if (cnt == CHUNK) {
                #pragma unroll 2
                for (int tt = 0; tt < CHUNK; ++tt) h = step(ab + tt * DH);
            } else {
                for (int tt = 0; tt < cnt; ++tt) h = step(ab + tt * DH);
            }
            __syncthreads();
        }

        // out[b] = dot(h_L, W_out[0,:]) + b_out[0]
        float o = h * W_out[l];
        #pragma unroll
        for (int off = 32; off > 0; off >>= 1) o += __shfl_xor(o, off, 64);
        if (l == 0) out[b] = o + b_out[0];
    } else {
        // ---------------- producers: a_t = W_xh @ x_t ----------------
        float wx[DH];
        #pragma unroll
        for (int i = 0; i < DH; ++i) wx[i] = W_xh[l * DH + i];

        auto produce = [&](int pc) {
            const int base = pc << 6;
            const int cnt  = min(CHUNK, L - base);
            for (int tt = wv - 1; tt < cnt; tt += NPROD) {
                const float* __restrict__ xt = xb + (size_t)(base + tt) * DH;
                float s0 = 0.f, s1 = 0.f, s2 = 0.f, s3 = 0.f;
                #pragma unroll
                for (int i = 0; i < DH; i += 4) {
                    // xt[i] is wave-uniform -> scalar loads + v_fma w/ SGPR src
                    s0 = fmaf(wx[i + 0], xt[i + 0], s0);
                    s1 = fmaf(wx[i + 1], xt[i + 1], s1);
                    s2 = fmaf(wx[i + 2], xt[i + 2], s2);
                    s3 = fmaf(wx[i + 3], xt[i + 3], s3);
                }
                a_buf[pc & 1][tt][l] = (s0 + s1) + (s2 + s3);
            }
        };

        if (nch > 0) produce(0);
        __syncthreads();
        for (int c = 0; c < nch; ++c) {
            if (c + 1 < nch) produce(c + 1);
            __syncthreads();
        }
    }
}

extern "C" void kernel_launch(void* const* d_in, const int* in_sizes, int n_in,
                              void* d_out, int out_size, void* d_ws, size_t ws_size,
                              hipStream_t stream) {
    const float* x     = (const float*)d_in[0];
    const int*   slen  = (const int*)  d_in[1];
    const float* W_xh  = (const float*)d_in[2];
    const float* W_hh  = (const float*)d_in[3];
    const float* W_out = (const float*)d_in[4];
    const float* b_out = (const float*)d_in[5];
    float* out = (float*)d_out;

    const int B = in_sizes[1];  // 256
    rnn_pk<<<dim3(B), dim3(64 * (NPROD + 1)), 0, stream>>>(
        x, slen, W_xh, W_hh, W_out, b_out, out);
}

// Round 4
// 402.603 us; speedup vs baseline: 4.5608x; 1.0051x over previous
//
#include <hip/hip_runtime.h>

// B=256, T=2048, D_IN=64, D_H=64, D_OUT=1
#define TSEQ  2048
#define DH    64
#define CHUNK 64
#define NPROD 3   // producer waves

typedef _Float16 h2 __attribute__((ext_vector_type(2)));
typedef _Float16 h8 __attribute__((ext_vector_type(8)));

__device__ inline float fdot2(h2 a, h2 b, float c) {
    return __builtin_amdgcn_fdot2(a, b, c, false);
}

// One block per batch. Wave 0: serial recurrence (h broadcast via f16 LDS).
// Waves 1..NPROD: produce a[t,:] = W_xh @ x_t into LDS double buffer.
__global__ __launch_bounds__(64 * (NPROD + 1), 1)
void rnn_f16(const float* __restrict__ x, const int* __restrict__ slen,
             const float* __restrict__ W_xh, const float* __restrict__ W_hh,
             const float* __restrict__ W_out, const float* __restrict__ b_out,
             float* __restrict__ out)
{
    __shared__ float a_buf[2][CHUNK][DH];            // 32 KiB
    __shared__ __align__(16) _Float16 hbuf[DH];      // h broadcast, f16

    const int b   = blockIdx.x;
    const int wv  = threadIdx.x >> 6;
    const int l   = threadIdx.x & 63;
    const int L   = slen[b];
    const int nch = (L + CHUNK - 1) / CHUNK;

    const float* __restrict__ xb = x + (size_t)b * TSEQ * DH;

    if (wv == 0) {
        // ---------------- consumer: the serial chain ----------------
        // Lane l owns W_hh row l as 32 packed f16 pairs (32 VGPRs).
        h2 w[32];
        #pragma unroll
        for (int k = 0; k < 32; ++k) {
            w[k].x = (_Float16)W_hh[l * DH + 2 * k];
            w[k].y = (_Float16)W_hh[l * DH + 2 * k + 1];
        }
        hbuf[l] = (_Float16)0.f;     // h_0 = 0
        float h = 0.f;
        __syncthreads();             // matches producers' post-produce(0) barrier

        const h8* hb = (const h8*)hbuf;   // 8 x ds_read_b128, wave-uniform (broadcast)

        auto step = [&](const float* __restrict__ ap) {
            const float aval = *ap;                   // ds_read_b32 (a_t[l]), off-chain
            float a0 = aval, a1 = 0.f, a2 = 0.f, a3 = 0.f;
            #pragma unroll
            for (int r = 0; r < 8; ++r) {
                const h8 v = hb[r];
                a0 = fdot2(__builtin_shufflevector(v, v, 0, 1), w[4 * r + 0], a0);
                a1 = fdot2(__builtin_shufflevector(v, v, 2, 3), w[4 * r + 1], a1);
                a2 = fdot2(__builtin_shufflevector(v, v, 4, 5), w[4 * r + 2], a2);
                a3 = fdot2(__builtin_shufflevector(v, v, 6, 7), w[4 * r + 3], a3);
            }
            float z = (a0 + a1) + (a2 + a3);
            // tanh(z) = 1 - 2/(exp(2z)+1)
            z = fminf(fmaxf(z, -15.0f), 15.0f);
            const float e2 = __expf(2.0f * z);
            const float hn = fmaf(-2.0f, __builtin_amdgcn_rcpf(e2 + 1.0f), 1.0f);
            hbuf[l] = (_Float16)hn;   // ds_write_b16; same-wave DS ops are in-order
            return hn;
        };

        for (int c = 0; c < nch; ++c) {
            const int base = c << 6;
            const int cnt  = min(CHUNK, L - base);
            const float* __restrict__ ab = &a_buf[c & 1][0][l];
            if (cnt == CHUNK) {
                #pragma unroll 4
                for (int tt = 0; tt < CHUNK; ++tt) h = step(ab + tt * DH);
            } else {
                for (int tt = 0; tt < cnt; ++tt) h = step(ab + tt * DH);
            }
            __syncthreads();
        }

        // out[b] = dot(h_L, W_out[0,:]) + b_out[0]
        float o = h * W_out[l];
        #pragma unroll
        for (int off = 32; off > 0; off >>= 1) o += __shfl_xor(o, off, 64);
        if (l == 0) out[b] = o + b_out[0];
    } else {
        // ---------------- producers: a_t = W_xh @ x_t ----------------
        float wx[DH];
        #pragma unroll
        for (int i = 0; i < DH; ++i) wx[i] = W_xh[l * DH + i];

        auto produce = [&](int pc) {
            const int base = pc << 6;
            const int cnt  = min(CHUNK, L - base);
            for (int tt = wv - 1; tt < cnt; tt += NPROD) {
                const float* __restrict__ xt = xb + (size_t)(base + tt) * DH;
                float s0 = 0.f, s1 = 0.f, s2 = 0.f, s3 = 0.f;
                #pragma unroll
                for (int i = 0; i < DH; i += 4) {
                    // xt[i] is wave-uniform -> scalar loads + v_fma w/ SGPR src
                    s0 = fmaf(wx[i + 0], xt[i + 0], s0);
                    s1 = fmaf(wx[i + 1], xt[i + 1], s1);
                    s2 = fmaf(wx[i + 2], xt[i + 2], s2);
                    s3 = fmaf(wx[i + 3], xt[i + 3], s3);
                }
                a_buf[pc & 1][tt][l] = (s0 + s1) + (s2 + s3);
            }
        };

        if (nch > 0) produce(0);
        __syncthreads();
        for (int c = 0; c < nch; ++c) {
            if (c + 1 < nch) produce(c + 1);
            __syncthreads();
        }
    }
}

extern "C" void kernel_launch(void* const* d_in, const int* in_sizes, int n_in,
                              void* d_out, int out_size, void* d_ws, size_t ws_size,
                              hipStream_t stream) {
    const float* x     = (const float*)d_in[0];
    const int*   slen  = (const int*)  d_in[1];
    const float* W_xh  = (const float*)d_in[2];
    const float* W_hh  = (const float*)d_in[3];
    const float* W_out = (const float*)d_in[4];
    const float* b_out = (const float*)d_in[5];
    float* out = (float*)d_out;

    const int B = in_sizes[1];  // 256
    rnn_f16<<<dim3(B), dim3(64 * (NPROD + 1)), 0, stream>>>(
        x, slen, W_xh, W_hh, W_out, b_out, out);
}